// Round 16
// baseline (159.013 us; speedup 1.0000x reference)
//
#include <hip/hip_runtime.h>
#include <hip/hip_bf16.h>
#include <math.h>

#define E 1024
#define H 16
#define HD 64
#define B 32
#define S 2048
#define CH 32           // 64-token chunks per batch row
#define CTOK (S / CH)   // 64 tokens per chunk
#define SUB 16          // tokens per sub-tile
#define NSUB (CTOK / SUB)  // 4
#define BHE (B * H * E)

typedef __attribute__((ext_vector_type(8))) short short8;
typedef __attribute__((ext_vector_type(4))) float f32x4;

__device__ __forceinline__ short f2bf(float f) {
    union { __hip_bfloat16 h; short s; } u;
    u.h = __float2bfloat16(f);
    return u.s;
}
__device__ __forceinline__ unsigned pack_bf2(float x, float y) {
    unsigned ux = (__float_as_uint(x) + 0x8000u) >> 16;
    unsigned uy = (__float_as_uint(y) + 0x8000u) & 0xffff0000u;
    return uy | ux;
}

// ---------------------------------------------------------------- q = Wq @ seed + bq   (256 blocks)
__global__ __launch_bounds__(256) void qproj_kernel(const float* __restrict__ W,
                                                    const float* __restrict__ bqkv,
                                                    const float* __restrict__ seed,
                                                    float* __restrict__ q) {
    int gw = (blockIdx.x * 256 + threadIdx.x) >> 6;  // e index
    int lane = threadIdx.x & 63;
    if (gw >= E) return;
    const float4* row = (const float4*)(W + (size_t)gw * E);
    const float4* sd = (const float4*)seed;
    float acc = 0.f;
#pragma unroll
    for (int k = 0; k < 4; ++k) {
        float4 w4 = row[k * 64 + lane];
        float4 s4 = sd[k * 64 + lane];
        acc = fmaf(w4.x, s4.x, acc); acc = fmaf(w4.y, s4.y, acc);
        acc = fmaf(w4.z, s4.z, acc); acc = fmaf(w4.w, s4.w, acc);
    }
#pragma unroll
    for (int off = 32; off > 0; off >>= 1) acc += __shfl_down(acc, off, 64);
    if (lane == 0) q[gw] = acc + bqkv[gw];
}

// ---------------------------------------------------------------- ubf[h][e] = bf16( scale * sum_d q[h*64+d] * Wk[h*64+d][e] )  (64 blocks)
__global__ __launch_bounds__(256) void uproj_kernel(const float* __restrict__ W,
                                                    const float* __restrict__ q,
                                                    short* __restrict__ ubf) {
    int h = blockIdx.y;
    int e = blockIdx.x * 256 + threadIdx.x;
    __shared__ float qs[HD];
    if (threadIdx.x < HD) qs[threadIdx.x] = q[h * HD + threadIdx.x];
    __syncthreads();
    const float* Wk = W + ((size_t)(E + h * HD)) * E + e;
    float acc = 0.f;
#pragma unroll 8
    for (int d = 0; d < HD; ++d) acc = fmaf(qs[d], Wk[(size_t)d * E], acc);
    ubf[(size_t)h * E + e] = f2bf(acc * 0.125f);  // 1/sqrt(64)
}

// ---------------------------------------------------------------- fused single-pass flash kernel per (chunk, b)
// 4 blocks/CU experiment (256 thr, SUB=16, ~38.5 KB LDS, 4 barrier domains/CU).
// R15 bug fixed: scp per-wave stride is 64 lanes -> (kq*4 + kg2)*16 + h, NOT (kq*16 + kg2).
__global__ __launch_bounds__(256, 4) void fused_kernel(const float* __restrict__ x,
                                                       const int* __restrict__ mask,
                                                       const short* __restrict__ ubf,
                                                       unsigned* __restrict__ partu,
                                                       float* __restrict__ mstat,
                                                       float* __restrict__ lstat) {
    int ss = blockIdx.x, b = blockIdx.y;
    __shared__ short xB[SUB * E];          // 32 KB bf16 [tok][e], XOR-swizzled
    __shared__ float scp[4 * 64 * 4];      // 4 KB cross-kq partials [wave][lane][reg]
    __shared__ float pcur[SUB * H];        // 1 KB  p of current sub-tile [tok][h]
    __shared__ int   mk[CTOK];             // 256 B
    __shared__ float mrun[H], lrun[H], rfac[H];
    __shared__ float wred[4][16];

    int tid = threadIdx.x, lane = tid & 63, wid = tid >> 6;

    if (tid < H) { mrun[tid] = -1e30f; lrun[tid] = 0.f; }
    if (tid < CTOK) mk[tid] = mask[(size_t)b * S + ss * CTOK + tid];

    int e8 = tid & 127;   // 8-float e-slice: e = e8*8
    int hg = tid >> 7;    // head group: heads hg*8 .. hg*8+7
    float4 accA[8], accB[8];   // [head in group]: e quad 0 / quad 1
#pragma unroll
    for (int h = 0; h < 8; ++h) {
        accA[h] = make_float4(0.f, 0.f, 0.f, 0.f);
        accB[h] = make_float4(0.f, 0.f, 0.f, 0.f);
    }

    __syncthreads();

    for (int sub = 0; sub < NSUB; ++sub) {
        int t0 = sub * SUB;

        // ---- stage x -> xB (16 tokens) ----
        {
            int tok = tid >> 4;        // 0..15
            int es  = tid & 15;
            const float* xr = x + ((size_t)b * S + ss * CTOK + t0 + tok) * E;
            bool live = mk[t0 + tok] != 0;
#pragma unroll
            for (int i = 0; i < 8; ++i) {
                int e0 = (es + i * 16) * 8;
                if (live) {
                    float4 lo = *(const float4*)(xr + e0);
                    float4 hi = *(const float4*)(xr + e0 + 4);
                    short8 v;
                    v[0] = f2bf(lo.x); v[1] = f2bf(lo.y); v[2] = f2bf(lo.z); v[3] = f2bf(lo.w);
                    v[4] = f2bf(hi.x); v[5] = f2bf(hi.y); v[6] = f2bf(hi.z); v[7] = f2bf(hi.w);
                    int byte = (tok * 2048 + e0 * 2) ^ ((tok & 7) << 4);
                    *(short8*)((char*)xB + byte) = v;
                }
            }
        }
        __syncthreads();

        // ---- MFMA scores: wave = kq (K-quarter), 16 tokens x 16 heads ----
        {
            int kq = wid;
            int tr = lane & 15, kg = lane >> 4;
            int tok = tr;
            f32x4 acc = {0.f, 0.f, 0.f, 0.f};
            const short* ub = ubf + (size_t)tr * E;
#pragma unroll
            for (int st = 0; st < 8; ++st) {
                int e0 = kq * 256 + st * 32 + kg * 8;
                int byte = (tok * 2048 + e0 * 2) ^ ((tok & 7) << 4);
                short8 a = *(const short8*)((char*)xB + byte);
                short8 bv = *(const short8*)(ub + e0);
                acc = __builtin_amdgcn_mfma_f32_16x16x32_bf16(a, bv, acc, 0, 0, 0);
            }
            *(f32x4*)&scp[(wid * 64 + lane) * 4] = acc;
        }
        __syncthreads();

        // ---- reduce over kq + online softmax update ----
        {
            int tok = tid >> 4, h = tid & 15;   // local token 0..15
            int r = tok & 3, kg2 = tok >> 2;
            float s = 0.f;
#pragma unroll
            for (int kq = 0; kq < 4; ++kq)
                s += scp[((kq * 4 + kg2) * 16 + h) * 4 + r];   // FIXED: wave stride = 64 lanes
            bool live = mk[t0 + tok] != 0;
            float sv = live ? s : -1e30f;
            float mx = sv;
            mx = fmaxf(mx, __shfl_xor(mx, 16, 64));
            mx = fmaxf(mx, __shfl_xor(mx, 32, 64));
            if (lane < 16) wred[wid][lane] = mx;
            __syncthreads();
            if (tid < 16) {
                float mt = wred[0][tid];
#pragma unroll
                for (int w = 1; w < 4; ++w) mt = fmaxf(mt, wred[w][tid]);
                float mo = mrun[tid];
                float mn = fmaxf(mo, mt);
                rfac[tid] = __expf(mo - mn);
                mrun[tid] = mn;
            }
            __syncthreads();
            float p = live ? __expf(s - mrun[h]) : 0.f;
            pcur[tok * 16 + h] = p;
            float ps = p;
            ps += __shfl_xor(ps, 16, 64);
            ps += __shfl_xor(ps, 32, 64);
            if (lane < 16) wred[wid][lane] = ps;
            __syncthreads();
            if (tid < 16) {
                float lt = 0.f;
#pragma unroll
                for (int w = 0; w < 4; ++w) lt += wred[w][tid];
                lrun[tid] = lrun[tid] * rfac[tid] + lt;
            }
        }
        __syncthreads();

        // ---- pool: rescale + accumulate (8 heads x 8 e per thread) ----
        {
            const float* rf = rfac + hg * 8;
#pragma unroll
            for (int h = 0; h < 8; ++h) {
                float r = rf[h];
                accA[h].x *= r; accA[h].y *= r; accA[h].z *= r; accA[h].w *= r;
                accB[h].x *= r; accB[h].y *= r; accB[h].z *= r; accB[h].w *= r;
            }
            int ebyte = e8 * 16;  // 8 bf16 = 16 bytes at e = e8*8
            for (int tok = 0; tok < SUB; ++tok) {
                if (!mk[t0 + tok]) continue;
                int byte = (tok * 2048 + ebyte) ^ ((tok & 7) << 4);
                uint4 xv = *(const uint4*)((char*)xB + byte);
                float xe0 = __uint_as_float(xv.x << 16);
                float xe1 = __uint_as_float(xv.x & 0xffff0000u);
                float xe2 = __uint_as_float(xv.y << 16);
                float xe3 = __uint_as_float(xv.y & 0xffff0000u);
                float xe4 = __uint_as_float(xv.z << 16);
                float xe5 = __uint_as_float(xv.z & 0xffff0000u);
                float xe6 = __uint_as_float(xv.w << 16);
                float xe7 = __uint_as_float(xv.w & 0xffff0000u);
                float4 p0 = *(const float4*)&pcur[tok * 16 + hg * 8];
                float4 p1 = *(const float4*)&pcur[tok * 16 + hg * 8 + 4];
#define POOLH(A, Bv, P) \
                A.x = fmaf(P, xe0, A.x); A.y = fmaf(P, xe1, A.y); \
                A.z = fmaf(P, xe2, A.z); A.w = fmaf(P, xe3, A.w); \
                Bv.x = fmaf(P, xe4, Bv.x); Bv.y = fmaf(P, xe5, Bv.y); \
                Bv.z = fmaf(P, xe6, Bv.z); Bv.w = fmaf(P, xe7, Bv.w);
                POOLH(accA[0], accB[0], p0.x)
                POOLH(accA[1], accB[1], p0.y)
                POOLH(accA[2], accB[2], p0.z)
                POOLH(accA[3], accB[3], p0.w)
                POOLH(accA[4], accB[4], p1.x)
                POOLH(accA[5], accB[5], p1.y)
                POOLH(accA[6], accB[6], p1.z)
                POOLH(accA[7], accB[7], p1.w)
#undef POOLH
            }
        }
        __syncthreads();  // protect xB/pcur before next stage
    }

    // ---- write unnormalized partial (packed bf16) + stats ----
    unsigned* pb = partu + ((size_t)ss * B + b) * (H * E / 2) + e8 * 4;
#pragma unroll
    for (int h = 0; h < 8; ++h) {
        uint4 v;
        v.x = pack_bf2(accA[h].x, accA[h].y);
        v.y = pack_bf2(accA[h].z, accA[h].w);
        v.z = pack_bf2(accB[h].x, accB[h].y);
        v.w = pack_bf2(accB[h].z, accB[h].w);
        *(uint4*)&pb[(size_t)(hg * 8 + h) * (E / 2)] = v;
    }
    if (tid < 16) {
        mstat[((size_t)ss * B + b) * H + tid] = mrun[tid];
        lstat[((size_t)ss * B + b) * H + tid] = lrun[tid];
    }
}

// ---------------------------------------------------------------- ctxc: combine bf16 chunk partials (online rescale) + Wv projection
__global__ __launch_bounds__(256) void ctxc_kernel(const float* __restrict__ W,
                                                   const float* __restrict__ bqkv,
                                                   const unsigned* __restrict__ partu,
                                                   const float* __restrict__ mstat,
                                                   const float* __restrict__ lstat,
                                                   float* __restrict__ ctx) {
    int cb = blockIdx.x, b = blockIdx.y, t = threadIdx.x;
    int h0 = cb * 4;
    __shared__ float xls[4 * E];  // 16 KB
    __shared__ float fs[4][CH];
    __shared__ float linv[4];
    if (t < 4) {
        int h = h0 + t;
        float mv[CH];
        float mg = -1e30f;
#pragma unroll
        for (int c = 0; c < CH; ++c) {
            mv[c] = mstat[((size_t)c * B + b) * H + h];
            mg = fmaxf(mg, mv[c]);
        }
        float l = 0.f;
#pragma unroll
        for (int c = 0; c < CH; ++c) {
            float fc = __expf(mv[c] - mg);
            fs[t][c] = fc;
            l = fmaf(fc, lstat[((size_t)c * B + b) * H + h], l);
        }
        linv[t] = 1.f / l;
    }
    __syncthreads();
    for (int i = t; i < 4 * E / 2; i += 256) {   // u32 elements: [hl][e2]
        int hl = i >> 9, e2 = i & 511;
        float sx = 0.f, sy = 0.f;
#pragma unroll 4
        for (int c = 0; c < CH; ++c) {
            float fc = fs[hl][c];
            unsigned v = partu[(((size_t)c * B + b) * H + h0 + hl) * (E / 2) + e2];
            sx = fmaf(fc, __uint_as_float(v << 16), sx);
            sy = fmaf(fc, __uint_as_float(v & 0xffff0000u), sy);
        }
        float li = linv[hl];
        xls[hl * E + e2 * 2] = sx * li;
        xls[hl * E + e2 * 2 + 1] = sy * li;
    }
    __syncthreads();
    int c = cb * 256 + t;
    int h = c >> 6;
    const float4* wr = (const float4*)(W + ((size_t)(2 * E + c)) * E);
    const float4* xl = (const float4*)(xls + (h - h0) * E);
    float acc = bqkv[2 * E + c];
#pragma unroll 4
    for (int e4 = 0; e4 < E / 4; ++e4) {
        float4 w = wr[e4], xv = xl[e4];
        acc = fmaf(w.x, xv.x, acc); acc = fmaf(w.y, xv.y, acc);
        acc = fmaf(w.z, xv.z, acc); acc = fmaf(w.w, xv.w, acc);
    }
    ctx[(size_t)b * E + c] = acc;
}

// ---------------------------------------------------------------- out[b][o] = ob[o] + Wo[o] . ctx[b]   (128 blocks)
__global__ __launch_bounds__(256) void outproj_kernel(const float* __restrict__ Wo,
                                                      const float* __restrict__ ob,
                                                      const float* __restrict__ ctx,
                                                      float* __restrict__ outpre) {
    int obk = blockIdx.x, b = blockIdx.y, t = threadIdx.x;
    int o = obk * 256 + t;
    __shared__ float cl[E];  // 4 KB
    const float4* cp = (const float4*)(ctx + (size_t)b * E);
    for (int i = t; i < E / 4; i += 256) ((float4*)cl)[i] = cp[i];
    __syncthreads();
    const float4* wr = (const float4*)(Wo + (size_t)o * E);
    const float4* cl4 = (const float4*)cl;
    float acc = ob[o];
#pragma unroll 4
    for (int e4 = 0; e4 < E / 4; ++e4) {
        float4 w = wr[e4], cv = cl4[e4];
        acc = fmaf(w.x, cv.x, acc); acc = fmaf(w.y, cv.y, acc);
        acc = fmaf(w.z, cv.z, acc); acc = fmaf(w.w, cv.w, acc);
    }
    outpre[(size_t)b * E + o] = acc;
}

// ---------------------------------------------------------------- LayerNorm over E per b
__global__ __launch_bounds__(256) void ln_kernel(const float* __restrict__ outpre,
                                                 const float* __restrict__ g,
                                                 const float* __restrict__ bb,
                                                 float* __restrict__ out) {
    int b = blockIdx.x, t = threadIdx.x, lane = t & 63, wid = t >> 6;
    const float4* row = (const float4*)(outpre + (size_t)b * E);
    float4 v = row[t];
    float s = v.x + v.y + v.z + v.w;
    float sq = v.x * v.x + v.y * v.y + v.z * v.z + v.w * v.w;
    __shared__ float rs[4], rq[4];
#pragma unroll
    for (int off = 32; off > 0; off >>= 1) {
        s += __shfl_down(s, off, 64);
        sq += __shfl_down(sq, off, 64);
    }
    if (lane == 0) { rs[wid] = s; rq[wid] = sq; }
    __syncthreads();
    s = rs[0] + rs[1] + rs[2] + rs[3];
    sq = rq[0] + rq[1] + rq[2] + rq[3];
    float mean = s * (1.f / E);
    float var = sq * (1.f / E) - mean * mean;
    float inv = rsqrtf(var + 1e-5f);
    float4 gv = ((const float4*)g)[t];
    float4 bv = ((const float4*)bb)[t];
    float4 o;
    o.x = (v.x - mean) * inv * gv.x + bv.x;
    o.y = (v.y - mean) * inv * gv.y + bv.y;
    o.z = (v.z - mean) * inv * gv.z + bv.z;
    o.w = (v.w - mean) * inv * gv.w + bv.w;
    ((float4*)(out + (size_t)b * E))[t] = o;
}

extern "C" void kernel_launch(void* const* d_in, const int* in_sizes, int n_in,
                              void* d_out, int out_size, void* d_ws, size_t ws_size,
                              hipStream_t stream) {
    const float* x    = (const float*)d_in[0];
    const int*   mask = (const int*)d_in[1];
    const float* seed = (const float*)d_in[2];
    const float* W    = (const float*)d_in[3];  // (3E, E)
    const float* bqkv = (const float*)d_in[4];  // (3E,)
    const float* Wo   = (const float*)d_in[5];  // (E, E)
    const float* ob   = (const float*)d_in[6];  // (E,)
    const float* g    = (const float*)d_in[7];
    const float* lb   = (const float*)d_in[8];
    float* out = (float*)d_out;

    float* ws = (float*)d_ws;
    float* q        = ws;                                   // E
    unsigned* partu = (unsigned*)(q + E);                   // CH*B*H*E/2 u32
    float* mstat    = (float*)(partu + (size_t)CH * BHE / 2);  // CH*B*H
    float* lstat    = mstat + (size_t)CH * B * H;           // CH*B*H
    short* ubf      = (short*)(lstat + (size_t)CH * B * H); // H*E bf16
    float* ctx      = (float*)(ubf + (size_t)H * E);        // B*E
    float* outpre   = ctx + (size_t)B * E;                  // B*E

    qproj_kernel<<<256, 256, 0, stream>>>(W, bqkv, seed, q);
    uproj_kernel<<<dim3(E / 256, H), 256, 0, stream>>>(W, q, ubf);
    fused_kernel<<<dim3(CH, B), 256, 0, stream>>>(x, mask, ubf, partu, mstat, lstat);
    ctxc_kernel<<<dim3(E / 256, B), 256, 0, stream>>>(W, bqkv, partu, mstat, lstat, ctx);
    outproj_kernel<<<dim3(E / 256, B), 256, 0, stream>>>(Wo, ob, ctx, outpre);
    ln_kernel<<<B, 256, 0, stream>>>(outpre, g, lb, out);
}

// Round 17
// 132.345 us; speedup vs baseline: 1.2015x; 1.2015x over previous
//
#include <hip/hip_runtime.h>
#include <hip/hip_bf16.h>
#include <math.h>

#define E 1024
#define H 16
#define HD 64
#define B 32
#define S 2048
#define CH 16           // 128-token chunks per batch row
#define CTOK (S / CH)   // 128 tokens per chunk
#define SUB 32          // tokens per sub-tile
#define NSUB (CTOK / SUB)
#define BHE (B * H * E)

typedef __attribute__((ext_vector_type(8))) short short8;
typedef __attribute__((ext_vector_type(4))) float f32x4;

__device__ __forceinline__ short f2bf(float f) {
    union { __hip_bfloat16 h; short s; } u;
    u.h = __float2bfloat16(f);
    return u.s;
}
__device__ __forceinline__ unsigned pack_bf2(float x, float y) {
    unsigned ux = (__float_as_uint(x) + 0x8000u) >> 16;
    unsigned uy = (__float_as_uint(y) + 0x8000u) & 0xffff0000u;
    return uy | ux;
}

// ---------------------------------------------------------------- q = Wq @ seed + bq   (256 blocks: latency-hiding parallelism)
__global__ __launch_bounds__(256) void qproj_kernel(const float* __restrict__ W,
                                                    const float* __restrict__ bqkv,
                                                    const float* __restrict__ seed,
                                                    float* __restrict__ q) {
    int gw = (blockIdx.x * 256 + threadIdx.x) >> 6;  // e index
    int lane = threadIdx.x & 63;
    if (gw >= E) return;
    const float4* row = (const float4*)(W + (size_t)gw * E);
    const float4* sd = (const float4*)seed;
    float acc = 0.f;
#pragma unroll
    for (int k = 0; k < 4; ++k) {
        float4 w4 = row[k * 64 + lane];
        float4 s4 = sd[k * 64 + lane];
        acc = fmaf(w4.x, s4.x, acc); acc = fmaf(w4.y, s4.y, acc);
        acc = fmaf(w4.z, s4.z, acc); acc = fmaf(w4.w, s4.w, acc);
    }
#pragma unroll
    for (int off = 32; off > 0; off >>= 1) acc += __shfl_down(acc, off, 64);
    if (lane == 0) q[gw] = acc + bqkv[gw];
}

// ---------------------------------------------------------------- ubf[h][e] = bf16( scale * sum_d q[h*64+d] * Wk[h*64+d][e] )  (64 blocks)
__global__ __launch_bounds__(256) void uproj_kernel(const float* __restrict__ W,
                                                    const float* __restrict__ q,
                                                    short* __restrict__ ubf) {
    int h = blockIdx.y;
    int e = blockIdx.x * 256 + threadIdx.x;
    __shared__ float qs[HD];
    if (threadIdx.x < HD) qs[threadIdx.x] = q[h * HD + threadIdx.x];
    __syncthreads();
    const float* Wk = W + ((size_t)(E + h * HD)) * E + e;
    float acc = 0.f;
#pragma unroll 8
    for (int d = 0; d < HD; ++d) acc = fmaf(qs[d], Wk[(size_t)d * E], acc);
    ubf[(size_t)h * E + e] = f2bf(acc * 0.125f);  // 1/sqrt(64)
}

// ---------------------------------------------------------------- fused single-pass flash kernel per (chunk, b)
// stage -> MFMA scores -> online softmax -> pool; partials stored packed bf16.
// Pool indexed: thread = (e4 = tid&255 -> 4 e, hg = tid>>8 -> 8 heads).
// Per token: 1 ds_read_b64 (x) + 1 ds_read_b128 (p, wave-uniform).
__global__ __launch_bounds__(512, 4) void fused_kernel(const float* __restrict__ x,
                                                       const int* __restrict__ mask,
                                                       const short* __restrict__ ubf,
                                                       unsigned* __restrict__ partu,
                                                       float* __restrict__ mstat,
                                                       float* __restrict__ lstat) {
    int ss = blockIdx.x, b = blockIdx.y;
    __shared__ short xB[SUB * E];          // 64 KB bf16 [tok][e], XOR-swizzled
    __shared__ float scp[8 * 64 * 4];      // 8 KB cross-kq partials [wave][lane][reg]
    __shared__ float pcur[SUB * H];        // 2 KB  p of current sub-tile [tok][h]
    __shared__ int   mk[CTOK];             // 512 B
    __shared__ float mrun[H], lrun[H], rfac[H];
    __shared__ float wred[8][16];

    int tid = threadIdx.x, lane = tid & 63, wid = tid >> 6;

    if (tid < H) { mrun[tid] = -1e30f; lrun[tid] = 0.f; }
    for (int i = tid; i < CTOK; i += 512) mk[i] = mask[(size_t)b * S + ss * CTOK + i];

    float4 a4[8];   // [head within group][4 e]
#pragma unroll
    for (int h = 0; h < 8; ++h) a4[h] = make_float4(0.f, 0.f, 0.f, 0.f);

    int pe4 = tid & 255, phg = tid >> 8;   // pool assignment (hg uniform per wave)

    __syncthreads();

    for (int sub = 0; sub < NSUB; ++sub) {
        int t0 = sub * SUB;

        // ---- stage x -> xB ----
        {
            int tok = tid >> 4;        // 0..31
            int es  = tid & 15;
            const float* xr = x + ((size_t)b * S + ss * CTOK + t0 + tok) * E;
            bool live = mk[t0 + tok] != 0;
#pragma unroll
            for (int i = 0; i < 8; ++i) {
                int e0 = (es + i * 16) * 8;
                if (live) {
                    float4 lo = *(const float4*)(xr + e0);
                    float4 hi = *(const float4*)(xr + e0 + 4);
                    short8 v;
                    v[0] = f2bf(lo.x); v[1] = f2bf(lo.y); v[2] = f2bf(lo.z); v[3] = f2bf(lo.w);
                    v[4] = f2bf(hi.x); v[5] = f2bf(hi.y); v[6] = f2bf(hi.z); v[7] = f2bf(hi.w);
                    int byte = (tok * 2048 + e0 * 2) ^ ((tok & 7) << 4);
                    *(short8*)((char*)xB + byte) = v;
                }
            }
        }
        __syncthreads();

        // ---- MFMA scores: wave (tw = wid&1, kq = wid>>1) ----
        {
            int tw = wid & 1, kq = wid >> 1;
            int tr = lane & 15, kg = lane >> 4;
            int tok = tw * 16 + tr;
            f32x4 acc = {0.f, 0.f, 0.f, 0.f};
            const short* ub = ubf + (size_t)tr * E;
#pragma unroll
            for (int st = 0; st < 8; ++st) {
                int e0 = kq * 256 + st * 32 + kg * 8;
                int byte = (tok * 2048 + e0 * 2) ^ ((tok & 7) << 4);
                short8 a = *(const short8*)((char*)xB + byte);
                short8 bv = *(const short8*)(ub + e0);
                acc = __builtin_amdgcn_mfma_f32_16x16x32_bf16(a, bv, acc, 0, 0, 0);
            }
            *(f32x4*)&scp[(wid * 64 + lane) * 4] = acc;
        }
        __syncthreads();

        // ---- reduce over kq + online softmax update ----
        {
            int tok = tid >> 4, h = tid & 15;   // local token 0..31
            int tw = tok >> 4, r = tok & 3, kg2 = (tok & 15) >> 2;
            float s = 0.f;
#pragma unroll
            for (int kq = 0; kq < 4; ++kq)
                s += scp[((kq * 2 + tw) * 64 + kg2 * 16 + h) * 4 + r];
            bool live = mk[t0 + tok] != 0;
            float sv = live ? s : -1e30f;
            float mx = sv;
            mx = fmaxf(mx, __shfl_xor(mx, 16, 64));
            mx = fmaxf(mx, __shfl_xor(mx, 32, 64));
            if (lane < 16) wred[wid][lane] = mx;
            __syncthreads();
            if (tid < 16) {
                float mt = wred[0][tid];
#pragma unroll
                for (int w = 1; w < 8; ++w) mt = fmaxf(mt, wred[w][tid]);
                float mo = mrun[tid];
                float mn = fmaxf(mo, mt);
                rfac[tid] = __expf(mo - mn);
                mrun[tid] = mn;
            }
            __syncthreads();
            float p = live ? __expf(s - mrun[h]) : 0.f;
            pcur[tok * 16 + h] = p;
            float ps = p;
            ps += __shfl_xor(ps, 16, 64);
            ps += __shfl_xor(ps, 32, 64);
            if (lane < 16) wred[wid][lane] = ps;
            __syncthreads();
            if (tid < 16) {
                float lt = 0.f;
#pragma unroll
                for (int w = 0; w < 8; ++w) lt += wred[w][tid];
                lrun[tid] = lrun[tid] * rfac[tid] + lt;
            }
        }
        __syncthreads();

        // ---- pool: rescale + accumulate from LDS ----
        {
            const float* rf = rfac + phg * 8;
#pragma unroll
            for (int h = 0; h < 8; ++h) {
                float r = rf[h];
                a4[h].x *= r; a4[h].y *= r; a4[h].z *= r; a4[h].w *= r;
            }
            int ebyte = pe4 * 8;  // 4 bf16 = 8 bytes at e = pe4*4
            for (int tok = 0; tok < SUB; ++tok) {
                if (!mk[t0 + tok]) continue;
                int byte = (tok * 2048 + ebyte) ^ ((tok & 7) << 4);
                uint2 xv = *(const uint2*)((char*)xB + byte);
                float xe0 = __uint_as_float(xv.x << 16);
                float xe1 = __uint_as_float(xv.x & 0xffff0000u);
                float xe2 = __uint_as_float(xv.y << 16);
                float xe3 = __uint_as_float(xv.y & 0xffff0000u);
                float4 p0 = *(const float4*)&pcur[tok * 16 + phg * 8];
                float4 p1 = *(const float4*)&pcur[tok * 16 + phg * 8 + 4];
                a4[0].x = fmaf(p0.x, xe0, a4[0].x); a4[0].y = fmaf(p0.x, xe1, a4[0].y);
                a4[0].z = fmaf(p0.x, xe2, a4[0].z); a4[0].w = fmaf(p0.x, xe3, a4[0].w);
                a4[1].x = fmaf(p0.y, xe0, a4[1].x); a4[1].y = fmaf(p0.y, xe1, a4[1].y);
                a4[1].z = fmaf(p0.y, xe2, a4[1].z); a4[1].w = fmaf(p0.y, xe3, a4[1].w);
                a4[2].x = fmaf(p0.z, xe0, a4[2].x); a4[2].y = fmaf(p0.z, xe1, a4[2].y);
                a4[2].z = fmaf(p0.z, xe2, a4[2].z); a4[2].w = fmaf(p0.z, xe3, a4[2].w);
                a4[3].x = fmaf(p0.w, xe0, a4[3].x); a4[3].y = fmaf(p0.w, xe1, a4[3].y);
                a4[3].z = fmaf(p0.w, xe2, a4[3].z); a4[3].w = fmaf(p0.w, xe3, a4[3].w);
                a4[4].x = fmaf(p1.x, xe0, a4[4].x); a4[4].y = fmaf(p1.x, xe1, a4[4].y);
                a4[4].z = fmaf(p1.x, xe2, a4[4].z); a4[4].w = fmaf(p1.x, xe3, a4[4].w);
                a4[5].x = fmaf(p1.y, xe0, a4[5].x); a4[5].y = fmaf(p1.y, xe1, a4[5].y);
                a4[5].z = fmaf(p1.y, xe2, a4[5].z); a4[5].w = fmaf(p1.y, xe3, a4[5].w);
                a4[6].x = fmaf(p1.z, xe0, a4[6].x); a4[6].y = fmaf(p1.z, xe1, a4[6].y);
                a4[6].z = fmaf(p1.z, xe2, a4[6].z); a4[6].w = fmaf(p1.z, xe3, a4[6].w);
                a4[7].x = fmaf(p1.w, xe0, a4[7].x); a4[7].y = fmaf(p1.w, xe1, a4[7].y);
                a4[7].z = fmaf(p1.w, xe2, a4[7].z); a4[7].w = fmaf(p1.w, xe3, a4[7].w);
            }
        }
        __syncthreads();  // protect xB before next stage
    }

    // ---- write unnormalized partial (packed bf16) + stats ----
    unsigned* pb = partu + ((size_t)ss * B + b) * (H * E / 2) + pe4 * 2;
#pragma unroll
    for (int h = 0; h < 8; ++h) {
        uint2 v;
        v.x = pack_bf2(a4[h].x, a4[h].y);
        v.y = pack_bf2(a4[h].z, a4[h].w);
        *(uint2*)&pb[(size_t)(phg * 8 + h) * (E / 2)] = v;
    }
    if (tid < 16) {
        mstat[((size_t)ss * B + b) * H + tid] = mrun[tid];
        lstat[((size_t)ss * B + b) * H + tid] = lrun[tid];
    }
}

// ---------------------------------------------------------------- ctxc: combine bf16 chunk partials (online rescale) + Wv projection
__global__ __launch_bounds__(256) void ctxc_kernel(const float* __restrict__ W,
                                                   const float* __restrict__ bqkv,
                                                   const unsigned* __restrict__ partu,
                                                   const float* __restrict__ mstat,
                                                   const float* __restrict__ lstat,
                                                   float* __restrict__ ctx) {
    int cb = blockIdx.x, b = blockIdx.y, t = threadIdx.x;
    int h0 = cb * 4;
    __shared__ float xls[4 * E];  // 16 KB
    __shared__ float fs[4][CH];
    __shared__ float linv[4];
    if (t < 4) {
        int h = h0 + t;
        float mv[CH];
        float mg = -1e30f;
#pragma unroll
        for (int c = 0; c < CH; ++c) {
            mv[c] = mstat[((size_t)c * B + b) * H + h];
            mg = fmaxf(mg, mv[c]);
        }
        float l = 0.f;
#pragma unroll
        for (int c = 0; c < CH; ++c) {
            float fc = __expf(mv[c] - mg);
            fs[t][c] = fc;
            l = fmaf(fc, lstat[((size_t)c * B + b) * H + h], l);
        }
        linv[t] = 1.f / l;
    }
    __syncthreads();
    for (int i = t; i < 4 * E / 2; i += 256) {   // u32 elements: [hl][e2]
        int hl = i >> 9, e2 = i & 511;
        float sx = 0.f, sy = 0.f;
#pragma unroll 4
        for (int c = 0; c < CH; ++c) {
            float fc = fs[hl][c];
            unsigned v = partu[(((size_t)c * B + b) * H + h0 + hl) * (E / 2) + e2];
            sx = fmaf(fc, __uint_as_float(v << 16), sx);
            sy = fmaf(fc, __uint_as_float(v & 0xffff0000u), sy);
        }
        float li = linv[hl];
        xls[hl * E + e2 * 2] = sx * li;
        xls[hl * E + e2 * 2 + 1] = sy * li;
    }
    __syncthreads();
    int c = cb * 256 + t;
    int h = c >> 6;
    const float4* wr = (const float4*)(W + ((size_t)(2 * E + c)) * E);
    const float4* xl = (const float4*)(xls + (h - h0) * E);
    float acc = bqkv[2 * E + c];
#pragma unroll 4
    for (int e4 = 0; e4 < E / 4; ++e4) {
        float4 w = wr[e4], xv = xl[e4];
        acc = fmaf(w.x, xv.x, acc); acc = fmaf(w.y, xv.y, acc);
        acc = fmaf(w.z, xv.z, acc); acc = fmaf(w.w, xv.w, acc);
    }
    ctx[(size_t)b * E + c] = acc;
}

// ---------------------------------------------------------------- out[b][o] = ob[o] + Wo[o] . ctx[b]   (128 blocks)
__global__ __launch_bounds__(256) void outproj_kernel(const float* __restrict__ Wo,
                                                      const float* __restrict__ ob,
                                                      const float* __restrict__ ctx,
                                                      float* __restrict__ outpre) {
    int obk = blockIdx.x, b = blockIdx.y, t = threadIdx.x;
    int o = obk * 256 + t;
    __shared__ float cl[E];  // 4 KB
    const float4* cp = (const float4*)(ctx + (size_t)b * E);
    for (int i = t; i < E / 4; i += 256) ((float4*)cl)[i] = cp[i];
    __syncthreads();
    const float4* wr = (const float4*)(Wo + (size_t)o * E);
    const float4* cl4 = (const float4*)cl;
    float acc = ob[o];
#pragma unroll 4
    for (int e4 = 0; e4 < E / 4; ++e4) {
        float4 w = wr[e4], cv = cl4[e4];
        acc = fmaf(w.x, cv.x, acc); acc = fmaf(w.y, cv.y, acc);
        acc = fmaf(w.z, cv.z, acc); acc = fmaf(w.w, cv.w, acc);
    }
    outpre[(size_t)b * E + o] = acc;
}

// ---------------------------------------------------------------- LayerNorm over E per b
__global__ __launch_bounds__(256) void ln_kernel(const float* __restrict__ outpre,
                                                 const float* __restrict__ g,
                                                 const float* __restrict__ bb,
                                                 float* __restrict__ out) {
    int b = blockIdx.x, t = threadIdx.x, lane = t & 63, wid = t >> 6;
    const float4* row = (const float4*)(outpre + (size_t)b * E);
    float4 v = row[t];
    float s = v.x + v.y + v.z + v.w;
    float sq = v.x * v.x + v.y * v.y + v.z * v.z + v.w * v.w;
    __shared__ float rs[4], rq[4];
#pragma unroll
    for (int off = 32; off > 0; off >>= 1) {
        s += __shfl_down(s, off, 64);
        sq += __shfl_down(sq, off, 64);
    }
    if (lane == 0) { rs[wid] = s; rq[wid] = sq; }
    __syncthreads();
    s = rs[0] + rs[1] + rs[2] + rs[3];
    sq = rq[0] + rq[1] + rq[2] + rq[3];
    float mean = s * (1.f / E);
    float var = sq * (1.f / E) - mean * mean;
    float inv = rsqrtf(var + 1e-5f);
    float4 gv = ((const float4*)g)[t];
    float4 bv = ((const float4*)bb)[t];
    float4 o;
    o.x = (v.x - mean) * inv * gv.x + bv.x;
    o.y = (v.y - mean) * inv * gv.y + bv.y;
    o.z = (v.z - mean) * inv * gv.z + bv.z;
    o.w = (v.w - mean) * inv * gv.w + bv.w;
    ((float4*)(out + (size_t)b * E))[t] = o;
}

extern "C" void kernel_launch(void* const* d_in, const int* in_sizes, int n_in,
                              void* d_out, int out_size, void* d_ws, size_t ws_size,
                              hipStream_t stream) {
    const float* x    = (const float*)d_in[0];
    const int*   mask = (const int*)d_in[1];
    const float* seed = (const float*)d_in[2];
    const float* W    = (const float*)d_in[3];  // (3E, E)
    const float* bqkv = (const float*)d_in[4];  // (3E,)
    const float* Wo   = (const float*)d_in[5];  // (E, E)
    const float* ob   = (const float*)d_in[6];  // (E,)
    const float* g    = (const float*)d_in[7];
    const float* lb   = (const float*)d_in[8];
    float* out = (float*)d_out;

    float* ws = (float*)d_ws;
    float* q        = ws;                                   // E
    unsigned* partu = (unsigned*)(q + E);                   // CH*B*H*E/2 u32
    float* mstat    = (float*)(partu + (size_t)CH * BHE / 2);  // CH*B*H
    float* lstat    = mstat + (size_t)CH * B * H;           // CH*B*H
    short* ubf      = (short*)(lstat + (size_t)CH * B * H); // H*E bf16
    float* ctx      = (float*)(ubf + (size_t)H * E);        // B*E
    float* outpre   = ctx + (size_t)B * E;                  // B*E

    qproj_kernel<<<256, 256, 0, stream>>>(W, bqkv, seed, q);
    uproj_kernel<<<dim3(E / 256, H), 256, 0, stream>>>(W, q, ubf);
    fused_kernel<<<dim3(CH, B), 512, 0, stream>>>(x, mask, ubf, partu, mstat, lstat);
    ctxc_kernel<<<dim3(E / 256, B), 256, 0, stream>>>(W, bqkv, partu, mstat, lstat, ctx);
    outproj_kernel<<<dim3(E / 256, B), 256, 0, stream>>>(Wo, ob, ctx, outpre);
    ln_kernel<<<B, 256, 0, stream>>>(outpre, g, lb, out);
}